// Round 9
// baseline (417.523 us; speedup 1.0000x reference)
//
#include <hip/hip_runtime.h>
#include <math.h>

constexpr int NV   = 100000;
constexpr int NEg  = 20000;
constexpr int NNZp = 1600000;
constexpr int NF   = 128;
constexpr int NH   = 64;
constexpr int NC   = 40;

constexpr int WE  = 64;                       // e-bucket width (2^6)
constexpr int NBE = (NEg + WE - 1) / WE;      // 313
constexpr int WV  = 256;                      // v-bucket width (2^8)
constexpr int NBV = (NV + WV - 1) / WV;       // 391
constexpr int SB  = NBE + NBV;                // 704 buckets total
constexpr int CAPS = 6400;                    // local_sort stage cap
constexpr int CH   = 4096;                    // partition chunk per block
constexpr int PBLK = (NNZp + CH - 1) / CH;    // 391
constexpr int NTILE_V = NV / 16;              // 6250 vertex tiles
constexpr int EVGRID  = 2048;                 // persistent blocks for ev gather

typedef __bf16 bf16x8 __attribute__((ext_vector_type(8)));
typedef float  f32x4  __attribute__((ext_vector_type(4)));
typedef float  f32x2  __attribute__((ext_vector_type(2)));
typedef unsigned short u16x8 __attribute__((ext_vector_type(8)));

// ---- bf16 <-> fp32 helpers (RNE) ----
__device__ __forceinline__ float bf2f(unsigned short u) {
    unsigned int x = ((unsigned int)u) << 16;
    return __builtin_bit_cast(float, x);
}
__device__ __forceinline__ unsigned short f2bf(float f) {
    unsigned int x = __builtin_bit_cast(unsigned int, f);
    x += 0x7fffu + ((x >> 16) & 1u);
    return (unsigned short)(x >> 16);
}
__device__ __forceinline__ ushort4 pack4(float a, float b, float c, float d) {
    ushort4 u; u.x = f2bf(a); u.y = f2bf(b); u.z = f2bf(c); u.w = f2bf(d);
    return u;
}
// dword-unpack accumulate: 2 unpack ops + 1 packed add per bf16 pair
__device__ __forceinline__ void accp(f32x2* a, uint4 w) {
    f32x2 t;
    t.x = __builtin_bit_cast(float, w.x << 16);
    t.y = __builtin_bit_cast(float, w.x & 0xffff0000u);
    a[0] += t;
    t.x = __builtin_bit_cast(float, w.y << 16);
    t.y = __builtin_bit_cast(float, w.y & 0xffff0000u);
    a[1] += t;
    t.x = __builtin_bit_cast(float, w.z << 16);
    t.y = __builtin_bit_cast(float, w.z & 0xffff0000u);
    a[2] += t;
    t.x = __builtin_bit_cast(float, w.w << 16);
    t.y = __builtin_bit_cast(float, w.w & 0xffff0000u);
    a[3] += t;
}

// shfl-based block exclusive scan over 512 threads (values beyond array = 0)
__device__ __forceinline__ int block_excl_scan(int val, int tid, int* wtot) {
    __syncthreads();                       // protect wtot reuse
    int x = val;
#pragma unroll
    for (int o = 1; o < 64; o <<= 1) {
        int y = __shfl_up(x, o);
        if ((tid & 63) >= o) x += y;
    }
    if ((tid & 63) == 63) wtot[tid >> 6] = x;
    __syncthreads();
    int add = 0;
    const int w = tid >> 6;
#pragma unroll
    for (int k = 0; k < 7; ++k) add += (k < w) ? wtot[k] : 0;
    return add + x - val;                  // exclusive prefix
}

// -------- coarse histograms (int4 input reads; persists per-block rows) -------
__global__ __launch_bounds__(256) void coarse_hist(const int* __restrict__ vertex,
                                                   const int* __restrict__ edges,
                                                   int* __restrict__ cnt_be,
                                                   int* __restrict__ cnt_bv,
                                                   int* __restrict__ bhist) {
    __shared__ int he[NBE], hv[NBV];
    for (int i = threadIdx.x; i < NBE; i += 256) he[i] = 0;
    for (int i = threadIdx.x; i < NBV; i += 256) hv[i] = 0;
    __syncthreads();
    const int base4 = blockIdx.x * (CH / 4);
    const int end4  = min(base4 + CH / 4, NNZp / 4);   // NNZp % 4 == 0
    const int4* e4 = (const int4*)edges;
    const int4* v4 = (const int4*)vertex;
    for (int i = base4 + threadIdx.x; i < end4; i += 256) {
        int4 e = e4[i];
        int4 v = v4[i];
        atomicAdd(&he[e.x >> 6], 1); atomicAdd(&he[e.y >> 6], 1);
        atomicAdd(&he[e.z >> 6], 1); atomicAdd(&he[e.w >> 6], 1);
        atomicAdd(&hv[v.x >> 8], 1); atomicAdd(&hv[v.y >> 8], 1);
        atomicAdd(&hv[v.z >> 8], 1); atomicAdd(&hv[v.w >> 8], 1);
    }
    __syncthreads();
    int* row = bhist + (size_t)blockIdx.x * SB;
    for (int i = threadIdx.x; i < NBE; i += 256) {
        int h = he[i];
        row[i] = h;
        if (h) atomicAdd(&cnt_be[i], h);
    }
    for (int i = threadIdx.x; i < NBV; i += 256) {
        int h = hv[i];
        row[NBE + i] = h;
        if (h) atomicAdd(&cnt_bv[i], h);
    }
}

// ---------------- tiny bucket scans ----------------
__global__ __launch_bounds__(512) void scan_buckets(const int* __restrict__ cnt_be,
                                                    const int* __restrict__ cnt_bv,
                                                    int* __restrict__ rsb_e,
                                                    int* __restrict__ rsb_v,
                                                    int* __restrict__ rs_e,
                                                    int* __restrict__ rs_v) {
    __shared__ int s[512];
    const int n      = (blockIdx.x == 0) ? NBE : NBV;
    const int* c     = (blockIdx.x == 0) ? cnt_be : cnt_bv;
    int* r           = (blockIdx.x == 0) ? rsb_e : rsb_v;
    const int t = threadIdx.x;
    int v = (t < n) ? c[t] : 0;
    s[t] = v;
    __syncthreads();
    for (int o = 1; o < 512; o <<= 1) {
        int u = (t >= o) ? s[t - o] : 0;
        __syncthreads();
        s[t] += u;
        __syncthreads();
    }
    if (t < n) r[t] = s[t] - v;
    if (t == 0) {
        r[n] = NNZp;
        if (blockIdx.x == 0) rs_e[NEg] = NNZp;
        else                 rs_v[NV]  = NNZp;
    }
}

// ------- per-bucket column scan over blocks: absolute base for (block,bucket) --
__global__ __launch_bounds__(512) void colscan(const int* __restrict__ bhist,
                                               const int* __restrict__ rsb_e,
                                               const int* __restrict__ rsb_v,
                                               int* __restrict__ abase) {
    __shared__ int s[512];
    const int f = blockIdx.x;             // bucket id (0..SB-1)
    const int t = threadIdx.x;
    int v = (t < PBLK) ? bhist[(size_t)t * SB + f] : 0;
    s[t] = v;
    __syncthreads();
    for (int o = 1; o < 512; o <<= 1) {
        int u = (t >= o) ? s[t - o] : 0;
        __syncthreads();
        s[t] += u;
        __syncthreads();
    }
    const int base = (f < NBE) ? rsb_e[f] : rsb_v[f - NBE];
    if (t < PBLK) abase[(size_t)t * SB + f] = base + (s[t] - v);
}

// ------- fused partition: single int4 input pass, bucket-ordered LDS staging --
__global__ __launch_bounds__(512) void partition_both(const int* __restrict__ vertex,
                                                      const int* __restrict__ edges,
                                                      const int* __restrict__ bhist,
                                                      const int* __restrict__ abase,
                                                      int* __restrict__ vid_out,
                                                      int* __restrict__ eid_out) {
    __shared__ int sval_e[CH], sdst_e[CH];
    __shared__ int sval_v[CH], sdst_v[CH];
    __shared__ int off_e[NBE], gb_e[NBE], cnt_e[NBE];
    __shared__ int off_v[NBV], gb_v[NBV], cnt_v[NBV];
    __shared__ int wtot[8];
    const int tid = threadIdx.x;
    const int b = blockIdx.x;
    const int* bh = bhist + (size_t)b * SB;
    const int* ab = abase + (size_t)b * SB;
    for (int i = tid; i < NBE; i += 512) { cnt_e[i] = 0; gb_e[i] = ab[i]; }
    for (int i = tid; i < NBV; i += 512) { cnt_v[i] = 0; gb_v[i] = ab[NBE + i]; }
    {
        int h  = (tid < NBE) ? bh[tid] : 0;
        int ex = block_excl_scan(h, tid, wtot);
        if (tid < NBE) off_e[tid] = ex;
    }
    {
        int h  = (tid < NBV) ? bh[NBE + tid] : 0;
        int ex = block_excl_scan(h, tid, wtot);
        if (tid < NBV) off_v[tid] = ex;
    }
    __syncthreads();
    const int base = b * CH;
    const int n    = min(base + CH, NNZp) - base;   // always multiple of 4
    const int n4   = n >> 2;
    const int4* e4 = (const int4*)(edges + base);
    const int4* v4 = (const int4*)(vertex + base);
    // rank elements, stage value+dest bucket-ordered (4 elements per step)
    for (int i = tid; i < n4; i += 512) {
        int4 ee = e4[i];
        int4 vv = v4[i];
        int ea[4] = {ee.x, ee.y, ee.z, ee.w};
        int va[4] = {vv.x, vv.y, vv.z, vv.w};
#pragma unroll
        for (int k = 0; k < 4; ++k) {
            int e = ea[k], v = va[k];
            int fe = e >> 6;
            int rk = atomicAdd(&cnt_e[fe], 1);
            int sl = off_e[fe] + rk;
            sval_e[sl] = (v << 6) | (e & 63);
            sdst_e[sl] = gb_e[fe] + rk;
            int fv = v >> 8;
            int rv = atomicAdd(&cnt_v[fv], 1);
            int s2 = off_v[fv] + rv;
            sval_v[s2] = (e << 8) | (v & 255);
            sdst_v[s2] = gb_v[fv] + rv;
        }
    }
    __syncthreads();
    // linear drain -> coalesced run writes
    for (int i = tid; i < n; i += 512) {
        vid_out[sdst_e[i]] = sval_e[i];
        eid_out[sdst_v[i]] = sval_v[i];
    }
}

// ------- fused per-bucket LDS counting sort -----------------------------------
// Output ids are PRE-SHIFTED by 6 (row element offset = id*NH).
__global__ __launch_bounds__(512) void local_sort_both(const int* __restrict__ rsb_e,
                                                       const int* __restrict__ rsb_v,
                                                       int* __restrict__ vid_buf,
                                                       int* __restrict__ eid_buf,
                                                       int* __restrict__ rs_e,
                                                       int* __restrict__ rs_v,
                                                       const float* __restrict__ degE,
                                                       float* __restrict__ scaleE) {
    __shared__ int stage[CAPS];
    __shared__ int hist[256], off[256], cnt2[256];
    const bool eside = blockIdx.x < NBE;
    const int b   = eside ? blockIdx.x : blockIdx.x - NBE;
    const int W   = eside ? 64 : 256;
    const int FB  = eside ? 6 : 8;
    const int NID = eside ? NEg : NV;
    const int* rsb = eside ? rsb_e : rsb_v;
    int* buf       = eside ? vid_buf : eid_buf;
    int* rs        = eside ? rs_e : rs_v;
    const int base = rsb[b];
    const int sz   = rsb[b + 1] - base;
    const int tid = threadIdx.x;
    if (tid < 256) { hist[tid] = 0; cnt2[tid] = 0; }
    __syncthreads();
    for (int t = tid; t < sz; t += 512) atomicAdd(&hist[buf[base + t] & (W - 1)], 1);
    __syncthreads();
    {
        int v = (tid < W) ? hist[tid] : 0;
        if (tid < W) off[tid] = v;
        __syncthreads();
        for (int o = 1; o < W; o <<= 1) {
            int u = (tid < W && tid >= o) ? off[tid - o] : 0;
            __syncthreads();
            if (tid < W) off[tid] += u;
            __syncthreads();
        }
        if (tid < W) off[tid] -= v;
    }
    if (tid < W) {
        int gid = b * W + tid;
        if (gid < NID) {
            rs[gid] = base + off[tid];
            if (eside) {
                int c = hist[tid];
                scaleE[gid] = degE[gid] / (float)(c < 1 ? 1 : c);
            }
        }
    }
    __syncthreads();
    for (int t = tid; t < sz; t += 512) {
        int w = buf[base + t];
        int f = w & (W - 1);
        int rk = off[f] + atomicAdd(&cnt2[f], 1);
        stage[rk] = (w >> FB) << 6;        // pre-multiplied by NH=64
    }
    __syncthreads();
    for (int t = tid; t < sz; t += 512) buf[base + t] = stage[t];
}

// ------- W fragments (B-operand layout, bf16): Ws MLPs + head + W0 ------------
__global__ __launch_bounds__(256) void make_wfrag(const float* __restrict__ Ws,
                                                  const float* __restrict__ Wout,
                                                  const float* __restrict__ W0,
                                                  unsigned short* __restrict__ frag) {
    int t = blockIdx.x * 256 + threadIdx.x;     // 3584 threads exactly
    int lane = t & 63;
    int g = t >> 6;                             // 0..55
    int quad = lane >> 4, cl = lane & 15;
    unsigned short o[8];
    if (g < 32) {
        int li = g >> 3, w = (g >> 1) & 3, kh = g & 1;
        int n = w * 16 + cl;
#pragma unroll
        for (int j = 0; j < 8; ++j) {
            int k = kh * 32 + quad * 8 + j;
            o[j] = f2bf(Ws[(size_t)li * NH * NH + k * NH + n]);
        }
    } else if (g < 40) {
        int w = (g - 32) >> 1, kh = g & 1;
        int n = w * 16 + cl;
#pragma unroll
        for (int j = 0; j < 8; ++j) {
            int k = kh * 32 + quad * 8 + j;
            o[j] = (n < NC) ? f2bf(Wout[k * NC + n]) : (unsigned short)0;
        }
    } else {
        int w = (g - 40) >> 2, kb = (g - 40) & 3;
        int n = w * 16 + cl;
#pragma unroll
        for (int j = 0; j < 8; ++j) {
            int k = kb * 32 + quad * 8 + j;
            o[j] = f2bf(W0[k * NH + n]);
        }
    }
    unsigned short* dst = frag + (size_t)g * 512 + lane * 8;
    *((ushort4*)dst)       = *(ushort4*)&o[0];
    *((ushort4*)(dst + 4)) = *(ushort4*)&o[4];
}

// ---------------- X = relu(x @ W0 + b0) via MFMA; Xbf = X0bf ------------------
__global__ __launch_bounds__(256) void gemm0_kernel(const float* __restrict__ x,
                                                    const unsigned short* __restrict__ W0frag,
                                                    const float* __restrict__ b0,
                                                    unsigned short* __restrict__ Xbf,
                                                    unsigned short* __restrict__ X0bf) {
    __shared__ unsigned short xs[16][136];    // bf16, stride 136 (16B-aligned rows)
    const int tid = threadIdx.x;
    const int r  = tid >> 4;
    const int c8 = (tid & 15) * 8;
    const int rowbase = blockIdx.x * 16;      // grid = NV/16 exact
    float4 p0 = *((const float4*)(x + (size_t)(rowbase + r) * NF + c8));
    float4 p1 = *((const float4*)(x + (size_t)(rowbase + r) * NF + c8 + 4));
    *((ushort4*)&xs[r][c8])     = pack4(p0.x, p0.y, p0.z, p0.w);
    *((ushort4*)&xs[r][c8 + 4]) = pack4(p1.x, p1.y, p1.z, p1.w);
    __syncthreads();
    const int lane = tid & 63;
    const int wv   = tid >> 6;
    const int quad = lane >> 4;
    const int cl   = lane & 15;
    f32x4 acc = {0.f, 0.f, 0.f, 0.f};
#pragma unroll
    for (int kb = 0; kb < 4; ++kb) {
        bf16x8 a = *((const bf16x8*)&xs[cl][kb * 32 + quad * 8]);
        bf16x8 b = *((const bf16x8*)(W0frag + ((size_t)(wv * 4 + kb) * 64 + lane) * 8));
        acc = __builtin_amdgcn_mfma_f32_16x16x32_bf16(a, b, acc, 0, 0, 0);
    }
    const int col = wv * 16 + cl;
    const float bo = b0[col];
#pragma unroll
    for (int p = 0; p < 4; ++p) {
        const int orow = quad * 4 + p;
        float o = acc[p] + bo;
        o = o > 0.f ? o : 0.f;
        unsigned short ob = f2bf(o);
        const size_t idx = (size_t)(rowbase + orow) * NH + col;
        Xbf[idx]  = ob;
        X0bf[idx] = ob;
    }
}

// ---------------- v->e gather: 2x 8-lane subgroups, stream-4, packed accum ----
__global__ __launch_bounds__(256) void gather_ve(const int* __restrict__ rs_e,
                                                 const int* __restrict__ vid_sorted,
                                                 const unsigned short* __restrict__ Xbf,
                                                 const float* __restrict__ scaleE,
                                                 unsigned short* __restrict__ Xebf) {
    const int tid = threadIdx.x;
    const int l8  = tid & 7;
    const int e = blockIdx.x * 16 + (tid >> 4);   // grid = NE/16 exact
    const int sb = rs_e[e];
    const int se = rs_e[e + 1];
    const int h  = (se - sb + 1) >> 1;
    int m        = sb + ((tid & 8) ? h : 0);
    const int en = (tid & 8) ? se : (sb + h);
    f32x2 a[4] = {{0.f, 0.f}, {0.f, 0.f}, {0.f, 0.f}, {0.f, 0.f}};
    if (m + 4 <= en) {
        int i0 = vid_sorted[m], i1 = vid_sorted[m + 1];
        int i2 = vid_sorted[m + 2], i3 = vid_sorted[m + 3];
        m += 4;
        while (m + 4 <= en) {
            int j0 = vid_sorted[m], j1 = vid_sorted[m + 1];
            int j2 = vid_sorted[m + 2], j3 = vid_sorted[m + 3];
            m += 4;
            uint4 p = *((const uint4*)(Xbf + i0) + l8);
            uint4 q = *((const uint4*)(Xbf + i1) + l8);
            uint4 u = *((const uint4*)(Xbf + i2) + l8);
            uint4 t = *((const uint4*)(Xbf + i3) + l8);
            accp(a, p); accp(a, q); accp(a, u); accp(a, t);
            i0 = j0; i1 = j1; i2 = j2; i3 = j3;
        }
        uint4 p = *((const uint4*)(Xbf + i0) + l8);
        uint4 q = *((const uint4*)(Xbf + i1) + l8);
        uint4 u = *((const uint4*)(Xbf + i2) + l8);
        uint4 t = *((const uint4*)(Xbf + i3) + l8);
        accp(a, p); accp(a, q); accp(a, u); accp(a, t);
    }
    for (; m < en; ++m) {
        uint4 p = *((const uint4*)(Xbf + vid_sorted[m]) + l8);
        accp(a, p);
    }
#pragma unroll
    for (int j = 0; j < 4; ++j) {            // combine halves
        a[j].x += __shfl_xor(a[j].x, 8);
        a[j].y += __shfl_xor(a[j].y, 8);
    }
    if (!(tid & 8)) {
        const float s = scaleE[e];
        u16x8 o;
#pragma unroll
        for (int j = 0; j < 4; ++j) {
            o[2 * j]     = f2bf(a[j].x * s);
            o[2 * j + 1] = f2bf(a[j].y * s);
        }
        *((u16x8*)(Xebf + (size_t)e * NH) + l8) = o;
    }
}

// -- e->v gather + normalize/residual + MFMA MLP (+head); persistent blocks ----
template <bool LAST>
__global__ __launch_bounds__(256) void gather_ev_update(const int* __restrict__ rs_v,
                                                        const int* __restrict__ eid_sorted,
                                                        const unsigned short* __restrict__ Xebf,
                                                        const float* __restrict__ degV,
                                                        const unsigned short* __restrict__ X0bf,
                                                        const unsigned short* __restrict__ WfragL,
                                                        unsigned short* __restrict__ Xbf,
                                                        float beta,
                                                        const unsigned short* __restrict__ WfragH,
                                                        const float* __restrict__ bout,
                                                        float* __restrict__ outp) {
    __shared__ unsigned short xis_bf[16][72];              // bf16, stride 72 (2-way only)
    __shared__ unsigned short xo_bf[LAST ? 16 * 72 : 1];   // final X (LAST only)
    __shared__ float lg[LAST ? 16 * 48 : 1];               // logits (LAST only)
    const int tid = threadIdx.x;
    const int l8  = tid & 7;
    const int r   = tid >> 4;
    const int lane = tid & 63;
    const int wv   = tid >> 6;
    const int quad = lane >> 4;
    const int cl   = lane & 15;
    // weight fragments are tile-invariant: load once
    bf16x8 bw0 = *((const bf16x8*)(WfragL + ((size_t)(wv * 2 + 0) * 64 + lane) * 8));
    bf16x8 bw1 = *((const bf16x8*)(WfragL + ((size_t)(wv * 2 + 1) * 64 + lane) * 8));

    for (int tile = blockIdx.x; tile < NTILE_V; tile += EVGRID) {
        const int v = tile * 16 + r;
        const int sb  = rs_v[v];
        const int sen = rs_v[v + 1];
        const float dv = degV[v];
        const int h  = (sen - sb + 1) >> 1;
        int m        = sb + ((tid & 8) ? h : 0);
        const int en = (tid & 8) ? sen : (sb + h);
        f32x2 a[4] = {{0.f, 0.f}, {0.f, 0.f}, {0.f, 0.f}, {0.f, 0.f}};
        if (m + 4 <= en) {
            int i0 = eid_sorted[m], i1 = eid_sorted[m + 1];
            int i2 = eid_sorted[m + 2], i3 = eid_sorted[m + 3];
            m += 4;
            while (m + 4 <= en) {
                int j0 = eid_sorted[m], j1 = eid_sorted[m + 1];
                int j2 = eid_sorted[m + 2], j3 = eid_sorted[m + 3];
                m += 4;
                uint4 p = *((const uint4*)(Xebf + i0) + l8);
                uint4 q = *((const uint4*)(Xebf + i1) + l8);
                uint4 u = *((const uint4*)(Xebf + i2) + l8);
                uint4 t = *((const uint4*)(Xebf + i3) + l8);
                accp(a, p); accp(a, q); accp(a, u); accp(a, t);
                i0 = j0; i1 = j1; i2 = j2; i3 = j3;
            }
            uint4 p = *((const uint4*)(Xebf + i0) + l8);
            uint4 q = *((const uint4*)(Xebf + i1) + l8);
            uint4 u = *((const uint4*)(Xebf + i2) + l8);
            uint4 t = *((const uint4*)(Xebf + i3) + l8);
            accp(a, p); accp(a, q); accp(a, u); accp(a, t);
        }
        for (; m < en; ++m) {
            uint4 p = *((const uint4*)(Xebf + eid_sorted[m]) + l8);
            accp(a, p);
        }
#pragma unroll
        for (int j = 0; j < 4; ++j) {        // combine halves, scale by degV
            a[j].x += __shfl_xor(a[j].x, 8);
            a[j].y += __shfl_xor(a[j].y, 8);
            a[j].x *= dv;
            a[j].y *= dv;
        }
        float sq = 0.f;
#pragma unroll
        for (int j = 0; j < 4; ++j) sq += a[j].x * a[j].x + a[j].y * a[j].y;
        sq += __shfl_xor(sq, 1);             // only 1/2/4: halves are duplicates
        sq += __shfl_xor(sq, 2);
        sq += __shfl_xor(sq, 4);
        float norm = sqrtf(sq);
        float inv = norm > 0.f ? 1.f / norm : 0.f;
        u16x8 x0 = *((const u16x8*)(X0bf + (size_t)v * NH) + l8);
        if (!(tid & 8)) {
            u16x8 o;
#pragma unroll
            for (int j = 0; j < 4; ++j) {
                o[2 * j]     = f2bf(0.9f * a[j].x * inv + 0.1f * bf2f(x0[2 * j]));
                o[2 * j + 1] = f2bf(0.9f * a[j].y * inv + 0.1f * bf2f(x0[2 * j + 1]));
            }
            *((u16x8*)&xis_bf[r][l8 * 8]) = o;
        }
        __syncthreads();

        // ---- MFMA MLP: g = xi @ Wl  (M=16, N=64, K=64) ----
        bf16x8 a0 = *((const bf16x8*)&xis_bf[cl][quad * 8]);
        bf16x8 a1 = *((const bf16x8*)&xis_bf[cl][32 + quad * 8]);
        f32x4 acc = {0.f, 0.f, 0.f, 0.f};
        acc = __builtin_amdgcn_mfma_f32_16x16x32_bf16(a0, bw0, acc, 0, 0, 0);
        acc = __builtin_amdgcn_mfma_f32_16x16x32_bf16(a1, bw1, acc, 0, 0, 0);

        const float ob = 1.f - beta;
        const int col = wv * 16 + cl;
#pragma unroll
        for (int p = 0; p < 4; ++p) {
            const int row = quad * 4 + p;
            float xiv = bf2f(xis_bf[row][col]);
            float o = ob * xiv + beta * acc[p];
            o = o > 0.f ? o : 0.f;
            if (!LAST) {
                Xbf[(size_t)(tile * 16 + row) * NH + col] = f2bf(o);
            } else {
                xo_bf[row * 72 + col] = f2bf(o);
            }
        }
        if (LAST) {
            __syncthreads();
            // ---- MFMA output head: logits = Xfinal @ Wout (N padded to 64) ----
            bf16x8 bh0 = *((const bf16x8*)(WfragH + ((size_t)(wv * 2 + 0) * 64 + lane) * 8));
            bf16x8 bh1 = *((const bf16x8*)(WfragH + ((size_t)(wv * 2 + 1) * 64 + lane) * 8));
            bf16x8 ah0 = *((const bf16x8*)&xo_bf[cl * 72 + quad * 8]);
            bf16x8 ah1 = *((const bf16x8*)&xo_bf[cl * 72 + 32 + quad * 8]);
            f32x4 acch = {0.f, 0.f, 0.f, 0.f};
            acch = __builtin_amdgcn_mfma_f32_16x16x32_bf16(ah0, bh0, acch, 0, 0, 0);
            acch = __builtin_amdgcn_mfma_f32_16x16x32_bf16(ah1, bh1, acch, 0, 0, 0);
            if (col < NC) {
                float bo = bout[col];
#pragma unroll
                for (int p = 0; p < 4; ++p) lg[(quad * 4 + p) * 48 + col] = acch[p] + bo;
            }
            __syncthreads();
            // ---- log_softmax: each wave handles 4 rows ----
            const int r0 = wv * 4;
            const bool act = lane < NC;
            float a0s = act ? lg[(r0 + 0) * 48 + lane] : -INFINITY;
            float a1s = act ? lg[(r0 + 1) * 48 + lane] : -INFINITY;
            float a2s = act ? lg[(r0 + 2) * 48 + lane] : -INFINITY;
            float a3s = act ? lg[(r0 + 3) * 48 + lane] : -INFINITY;
            float m0 = a0s, m1 = a1s, m2 = a2s, m3 = a3s;
#pragma unroll
            for (int o = 32; o; o >>= 1) {
                m0 = fmaxf(m0, __shfl_xor(m0, o));
                m1 = fmaxf(m1, __shfl_xor(m1, o));
                m2 = fmaxf(m2, __shfl_xor(m2, o));
                m3 = fmaxf(m3, __shfl_xor(m3, o));
            }
            float e0 = act ? expf(a0s - m0) : 0.f;
            float e1 = act ? expf(a1s - m1) : 0.f;
            float e2 = act ? expf(a2s - m2) : 0.f;
            float e3 = act ? expf(a3s - m3) : 0.f;
#pragma unroll
            for (int o = 32; o; o >>= 1) {
                e0 += __shfl_xor(e0, o);
                e1 += __shfl_xor(e1, o);
                e2 += __shfl_xor(e2, o);
                e3 += __shfl_xor(e3, o);
            }
            if (act) {
                const size_t vb = (size_t)(tile * 16 + r0) * NC + lane;
                outp[vb + 0 * NC] = a0s - m0 - logf(e0);
                outp[vb + 1 * NC] = a1s - m1 - logf(e1);
                outp[vb + 2 * NC] = a2s - m2 - logf(e2);
                outp[vb + 3 * NC] = a3s - m3 - logf(e3);
            }
        }
        __syncthreads();   // protect xis_bf (and xo_bf/lg) reuse across tiles
    }
}

extern "C" void kernel_launch(void* const* d_in, const int* in_sizes, int n_in,
                              void* d_out, int out_size, void* d_ws, size_t ws_size,
                              hipStream_t stream) {
    const float* x    = (const float*)d_in[0];
    const float* degE = (const float*)d_in[1];
    const float* degV = (const float*)d_in[2];
    const float* W0   = (const float*)d_in[3];
    const float* b0   = (const float*)d_in[4];
    const float* Ws   = (const float*)d_in[5];
    const float* Wout = (const float*)d_in[6];
    const float* bout = (const float*)d_in[7];
    const int* vertex = (const int*)d_in[8];
    const int* edges  = (const int*)d_in[9];
    float* out = (float*)d_out;

    // workspace layout
    float* scaleE = (float*)d_ws;                              // NEg
    unsigned short* Xbf  = (unsigned short*)(scaleE + NEg);    // NV*NH bf16
    unsigned short* X0bf = Xbf + (size_t)NV * NH;
    unsigned short* Xebf = X0bf + (size_t)NV * NH;             // NE*NH bf16
    int* cnt_be = (int*)(Xebf + (size_t)NEg * NH);
    int* cnt_bv = cnt_be + NBE;
    int* rsb_e  = cnt_bv + NBV;
    int* rsb_v  = rsb_e + (NBE + 1);
    int* rs_e   = rsb_v + (NBV + 1);
    int* rs_v   = rs_e + (NEg + 1);
    int* vid_sorted = rs_v + (NV + 1);                         // NNZ
    int* eid_sorted = vid_sorted + NNZp;                       // NNZ
    unsigned short* Wfrag = (unsigned short*)(eid_sorted + NNZp);  // 56 groups * 512
    int* bhist = (int*)(Wfrag + 56 * 512);                     // PBLK*SB
    int* abase = bhist + (size_t)PBLK * SB;                    // PBLK*SB

    // ---- CSR build + weight fragments ----
    hipMemsetAsync(cnt_be, 0, (size_t)(NBE + NBV) * sizeof(int), stream);
    make_wfrag<<<14, 256, 0, stream>>>(Ws, Wout, W0, Wfrag);
    coarse_hist<<<PBLK, 256, 0, stream>>>(vertex, edges, cnt_be, cnt_bv, bhist);
    scan_buckets<<<2, 512, 0, stream>>>(cnt_be, cnt_bv, rsb_e, rsb_v, rs_e, rs_v);
    colscan<<<SB, 512, 0, stream>>>(bhist, rsb_e, rsb_v, abase);
    partition_both<<<PBLK, 512, 0, stream>>>(vertex, edges, bhist, abase,
                                             vid_sorted, eid_sorted);
    local_sort_both<<<NBE + NBV, 512, 0, stream>>>(rsb_e, rsb_v, vid_sorted, eid_sorted,
                                                   rs_e, rs_v, degE, scaleE);

    // ---- X = relu(x @ W0 + b0) via MFMA ----
    gemm0_kernel<<<NV / 16, 256, 0, stream>>>(x, Wfrag + 40 * 512, b0, Xbf, X0bf);

    const float betas[4] = {logf(0.5f / 1.f + 1.f), logf(0.5f / 2.f + 1.f),
                            logf(0.5f / 3.f + 1.f), logf(0.5f / 4.f + 1.f)};

    for (int i = 0; i < 3; ++i) {
        gather_ve<<<NEg / 16, 256, 0, stream>>>(rs_e, vid_sorted, Xbf, scaleE, Xebf);
        gather_ev_update<false><<<EVGRID, 256, 0, stream>>>(rs_v, eid_sorted, Xebf, degV,
                                                            X0bf, Wfrag + (size_t)i * 4096,
                                                            Xbf, betas[i],
                                                            nullptr, nullptr, nullptr);
    }
    gather_ve<<<NEg / 16, 256, 0, stream>>>(rs_e, vid_sorted, Xbf, scaleE, Xebf);
    gather_ev_update<true><<<EVGRID, 256, 0, stream>>>(rs_v, eid_sorted, Xebf, degV,
                                                       X0bf, Wfrag + (size_t)3 * 4096,
                                                       Xbf, betas[3],
                                                       Wfrag + 16384, bout, out);
}

// Round 10
// 378.930 us; speedup vs baseline: 1.1018x; 1.1018x over previous
//
#include <hip/hip_runtime.h>
#include <math.h>

constexpr int NV   = 100000;
constexpr int NEg  = 20000;
constexpr int NNZp = 1600000;
constexpr int NF   = 128;
constexpr int NH   = 64;
constexpr int NC   = 40;

constexpr int WE  = 64;                       // e-bucket width (2^6)
constexpr int NBE = (NEg + WE - 1) / WE;      // 313
constexpr int WV  = 256;                      // v-bucket width (2^8)
constexpr int NBV = (NV + WV - 1) / WV;       // 391
constexpr int SB  = NBE + NBV;                // 704 buckets total
constexpr int CAPS = 6400;                    // local_sort stage cap
constexpr int CH   = 4096;                    // partition chunk per block
constexpr int PBLK = (NNZp + CH - 1) / CH;    // 391

typedef __bf16 bf16x8 __attribute__((ext_vector_type(8)));
typedef float  f32x4  __attribute__((ext_vector_type(4)));
typedef float  f32x2  __attribute__((ext_vector_type(2)));
typedef unsigned short u16x8 __attribute__((ext_vector_type(8)));

// ---- bf16 <-> fp32 helpers (RNE) ----
__device__ __forceinline__ float bf2f(unsigned short u) {
    unsigned int x = ((unsigned int)u) << 16;
    return __builtin_bit_cast(float, x);
}
__device__ __forceinline__ unsigned short f2bf(float f) {
    unsigned int x = __builtin_bit_cast(unsigned int, f);
    x += 0x7fffu + ((x >> 16) & 1u);
    return (unsigned short)(x >> 16);
}
__device__ __forceinline__ ushort4 pack4(float a, float b, float c, float d) {
    ushort4 u; u.x = f2bf(a); u.y = f2bf(b); u.z = f2bf(c); u.w = f2bf(d);
    return u;
}
// dword-unpack accumulate: 2 unpack ops + 1 packed add per bf16 pair
__device__ __forceinline__ void accp(f32x2* a, uint4 w) {
    f32x2 t;
    t.x = __builtin_bit_cast(float, w.x << 16);
    t.y = __builtin_bit_cast(float, w.x & 0xffff0000u);
    a[0] += t;
    t.x = __builtin_bit_cast(float, w.y << 16);
    t.y = __builtin_bit_cast(float, w.y & 0xffff0000u);
    a[1] += t;
    t.x = __builtin_bit_cast(float, w.z << 16);
    t.y = __builtin_bit_cast(float, w.z & 0xffff0000u);
    a[2] += t;
    t.x = __builtin_bit_cast(float, w.w << 16);
    t.y = __builtin_bit_cast(float, w.w & 0xffff0000u);
    a[3] += t;
}

// shfl-based block exclusive scan over 512 threads (values beyond array = 0)
__device__ __forceinline__ int block_excl_scan(int val, int tid, int* wtot) {
    __syncthreads();                       // protect wtot reuse
    int x = val;
#pragma unroll
    for (int o = 1; o < 64; o <<= 1) {
        int y = __shfl_up(x, o);
        if ((tid & 63) >= o) x += y;
    }
    if ((tid & 63) == 63) wtot[tid >> 6] = x;
    __syncthreads();
    int add = 0;
    const int w = tid >> 6;
#pragma unroll
    for (int k = 0; k < 7; ++k) add += (k < w) ? wtot[k] : 0;
    return add + x - val;                  // exclusive prefix
}

// -------- coarse histograms (int4 input reads; persists per-block rows) -------
__global__ __launch_bounds__(256) void coarse_hist(const int* __restrict__ vertex,
                                                   const int* __restrict__ edges,
                                                   int* __restrict__ cnt_be,
                                                   int* __restrict__ cnt_bv,
                                                   int* __restrict__ bhist) {
    __shared__ int he[NBE], hv[NBV];
    for (int i = threadIdx.x; i < NBE; i += 256) he[i] = 0;
    for (int i = threadIdx.x; i < NBV; i += 256) hv[i] = 0;
    __syncthreads();
    const int base4 = blockIdx.x * (CH / 4);
    const int end4  = min(base4 + CH / 4, NNZp / 4);   // NNZp % 4 == 0
    const int4* e4 = (const int4*)edges;
    const int4* v4 = (const int4*)vertex;
    for (int i = base4 + threadIdx.x; i < end4; i += 256) {
        int4 e = e4[i];
        int4 v = v4[i];
        atomicAdd(&he[e.x >> 6], 1); atomicAdd(&he[e.y >> 6], 1);
        atomicAdd(&he[e.z >> 6], 1); atomicAdd(&he[e.w >> 6], 1);
        atomicAdd(&hv[v.x >> 8], 1); atomicAdd(&hv[v.y >> 8], 1);
        atomicAdd(&hv[v.z >> 8], 1); atomicAdd(&hv[v.w >> 8], 1);
    }
    __syncthreads();
    int* row = bhist + (size_t)blockIdx.x * SB;
    for (int i = threadIdx.x; i < NBE; i += 256) {
        int h = he[i];
        row[i] = h;
        if (h) atomicAdd(&cnt_be[i], h);
    }
    for (int i = threadIdx.x; i < NBV; i += 256) {
        int h = hv[i];
        row[NBE + i] = h;
        if (h) atomicAdd(&cnt_bv[i], h);
    }
}

// ---------------- tiny bucket scans ----------------
__global__ __launch_bounds__(512) void scan_buckets(const int* __restrict__ cnt_be,
                                                    const int* __restrict__ cnt_bv,
                                                    int* __restrict__ rsb_e,
                                                    int* __restrict__ rsb_v,
                                                    int* __restrict__ rs_e,
                                                    int* __restrict__ rs_v) {
    __shared__ int s[512];
    const int n      = (blockIdx.x == 0) ? NBE : NBV;
    const int* c     = (blockIdx.x == 0) ? cnt_be : cnt_bv;
    int* r           = (blockIdx.x == 0) ? rsb_e : rsb_v;
    const int t = threadIdx.x;
    int v = (t < n) ? c[t] : 0;
    s[t] = v;
    __syncthreads();
    for (int o = 1; o < 512; o <<= 1) {
        int u = (t >= o) ? s[t - o] : 0;
        __syncthreads();
        s[t] += u;
        __syncthreads();
    }
    if (t < n) r[t] = s[t] - v;
    if (t == 0) {
        r[n] = NNZp;
        if (blockIdx.x == 0) rs_e[NEg] = NNZp;
        else                 rs_v[NV]  = NNZp;
    }
}

// ------- per-bucket column scan over blocks: absolute base for (block,bucket) --
__global__ __launch_bounds__(512) void colscan(const int* __restrict__ bhist,
                                               const int* __restrict__ rsb_e,
                                               const int* __restrict__ rsb_v,
                                               int* __restrict__ abase) {
    __shared__ int s[512];
    const int f = blockIdx.x;             // bucket id (0..SB-1)
    const int t = threadIdx.x;
    int v = (t < PBLK) ? bhist[(size_t)t * SB + f] : 0;
    s[t] = v;
    __syncthreads();
    for (int o = 1; o < 512; o <<= 1) {
        int u = (t >= o) ? s[t - o] : 0;
        __syncthreads();
        s[t] += u;
        __syncthreads();
    }
    const int base = (f < NBE) ? rsb_e[f] : rsb_v[f - NBE];
    if (t < PBLK) abase[(size_t)t * SB + f] = base + (s[t] - v);
}

// ------- fused partition: single int4 input pass, bucket-ordered LDS staging --
__global__ __launch_bounds__(512) void partition_both(const int* __restrict__ vertex,
                                                      const int* __restrict__ edges,
                                                      const int* __restrict__ bhist,
                                                      const int* __restrict__ abase,
                                                      int* __restrict__ vid_out,
                                                      int* __restrict__ eid_out) {
    __shared__ int sval_e[CH], sdst_e[CH];
    __shared__ int sval_v[CH], sdst_v[CH];
    __shared__ int off_e[NBE], gb_e[NBE], cnt_e[NBE];
    __shared__ int off_v[NBV], gb_v[NBV], cnt_v[NBV];
    __shared__ int wtot[8];
    const int tid = threadIdx.x;
    const int b = blockIdx.x;
    const int* bh = bhist + (size_t)b * SB;
    const int* ab = abase + (size_t)b * SB;
    for (int i = tid; i < NBE; i += 512) { cnt_e[i] = 0; gb_e[i] = ab[i]; }
    for (int i = tid; i < NBV; i += 512) { cnt_v[i] = 0; gb_v[i] = ab[NBE + i]; }
    {
        int h  = (tid < NBE) ? bh[tid] : 0;
        int ex = block_excl_scan(h, tid, wtot);
        if (tid < NBE) off_e[tid] = ex;
    }
    {
        int h  = (tid < NBV) ? bh[NBE + tid] : 0;
        int ex = block_excl_scan(h, tid, wtot);
        if (tid < NBV) off_v[tid] = ex;
    }
    __syncthreads();
    const int base = b * CH;
    const int n    = min(base + CH, NNZp) - base;   // always multiple of 4
    const int n4   = n >> 2;
    const int4* e4 = (const int4*)(edges + base);
    const int4* v4 = (const int4*)(vertex + base);
    // rank elements, stage value+dest bucket-ordered (4 elements per step)
    for (int i = tid; i < n4; i += 512) {
        int4 ee = e4[i];
        int4 vv = v4[i];
        int ea[4] = {ee.x, ee.y, ee.z, ee.w};
        int va[4] = {vv.x, vv.y, vv.z, vv.w};
#pragma unroll
        for (int k = 0; k < 4; ++k) {
            int e = ea[k], v = va[k];
            int fe = e >> 6;
            int rk = atomicAdd(&cnt_e[fe], 1);
            int sl = off_e[fe] + rk;
            sval_e[sl] = (v << 6) | (e & 63);
            sdst_e[sl] = gb_e[fe] + rk;
            int fv = v >> 8;
            int rv = atomicAdd(&cnt_v[fv], 1);
            int s2 = off_v[fv] + rv;
            sval_v[s2] = (e << 8) | (v & 255);
            sdst_v[s2] = gb_v[fv] + rv;
        }
    }
    __syncthreads();
    // linear drain -> coalesced run writes
    for (int i = tid; i < n; i += 512) {
        vid_out[sdst_e[i]] = sval_e[i];
        eid_out[sdst_v[i]] = sval_v[i];
    }
}

// ------- fused per-bucket LDS counting sort -----------------------------------
// Output ids are PRE-SHIFTED by 6 (row element offset = id*NH).
__global__ __launch_bounds__(512) void local_sort_both(const int* __restrict__ rsb_e,
                                                       const int* __restrict__ rsb_v,
                                                       int* __restrict__ vid_buf,
                                                       int* __restrict__ eid_buf,
                                                       int* __restrict__ rs_e,
                                                       int* __restrict__ rs_v,
                                                       const float* __restrict__ degE,
                                                       float* __restrict__ scaleE) {
    __shared__ int stage[CAPS];
    __shared__ int hist[256], off[256], cnt2[256];
    const bool eside = blockIdx.x < NBE;
    const int b   = eside ? blockIdx.x : blockIdx.x - NBE;
    const int W   = eside ? 64 : 256;
    const int FB  = eside ? 6 : 8;
    const int NID = eside ? NEg : NV;
    const int* rsb = eside ? rsb_e : rsb_v;
    int* buf       = eside ? vid_buf : eid_buf;
    int* rs        = eside ? rs_e : rs_v;
    const int base = rsb[b];
    const int sz   = rsb[b + 1] - base;
    const int tid = threadIdx.x;
    if (tid < 256) { hist[tid] = 0; cnt2[tid] = 0; }
    __syncthreads();
    for (int t = tid; t < sz; t += 512) atomicAdd(&hist[buf[base + t] & (W - 1)], 1);
    __syncthreads();
    {
        int v = (tid < W) ? hist[tid] : 0;
        if (tid < W) off[tid] = v;
        __syncthreads();
        for (int o = 1; o < W; o <<= 1) {
            int u = (tid < W && tid >= o) ? off[tid - o] : 0;
            __syncthreads();
            if (tid < W) off[tid] += u;
            __syncthreads();
        }
        if (tid < W) off[tid] -= v;
    }
    if (tid < W) {
        int gid = b * W + tid;
        if (gid < NID) {
            rs[gid] = base + off[tid];
            if (eside) {
                int c = hist[tid];
                scaleE[gid] = degE[gid] / (float)(c < 1 ? 1 : c);
            }
        }
    }
    __syncthreads();
    for (int t = tid; t < sz; t += 512) {
        int w = buf[base + t];
        int f = w & (W - 1);
        int rk = off[f] + atomicAdd(&cnt2[f], 1);
        stage[rk] = (w >> FB) << 6;        // pre-multiplied by NH=64
    }
    __syncthreads();
    for (int t = tid; t < sz; t += 512) buf[base + t] = stage[t];
}

// ------- W fragments (B-operand layout, bf16): Ws MLPs + head + W0 ------------
__global__ __launch_bounds__(256) void make_wfrag(const float* __restrict__ Ws,
                                                  const float* __restrict__ Wout,
                                                  const float* __restrict__ W0,
                                                  unsigned short* __restrict__ frag) {
    int t = blockIdx.x * 256 + threadIdx.x;     // 3584 threads exactly
    int lane = t & 63;
    int g = t >> 6;                             // 0..55
    int quad = lane >> 4, cl = lane & 15;
    unsigned short o[8];
    if (g < 32) {
        int li = g >> 3, w = (g >> 1) & 3, kh = g & 1;
        int n = w * 16 + cl;
#pragma unroll
        for (int j = 0; j < 8; ++j) {
            int k = kh * 32 + quad * 8 + j;
            o[j] = f2bf(Ws[(size_t)li * NH * NH + k * NH + n]);
        }
    } else if (g < 40) {
        int w = (g - 32) >> 1, kh = g & 1;
        int n = w * 16 + cl;
#pragma unroll
        for (int j = 0; j < 8; ++j) {
            int k = kh * 32 + quad * 8 + j;
            o[j] = (n < NC) ? f2bf(Wout[k * NC + n]) : (unsigned short)0;
        }
    } else {
        int w = (g - 40) >> 2, kb = (g - 40) & 3;
        int n = w * 16 + cl;
#pragma unroll
        for (int j = 0; j < 8; ++j) {
            int k = kb * 32 + quad * 8 + j;
            o[j] = f2bf(W0[k * NH + n]);
        }
    }
    unsigned short* dst = frag + (size_t)g * 512 + lane * 8;
    *((ushort4*)dst)       = *(ushort4*)&o[0];
    *((ushort4*)(dst + 4)) = *(ushort4*)&o[4];
}

// ---------------- X = relu(x @ W0 + b0) via MFMA; Xbf = X0bf ------------------
__global__ __launch_bounds__(256) void gemm0_kernel(const float* __restrict__ x,
                                                    const unsigned short* __restrict__ W0frag,
                                                    const float* __restrict__ b0,
                                                    unsigned short* __restrict__ Xbf,
                                                    unsigned short* __restrict__ X0bf) {
    __shared__ unsigned short xs[16][136];    // bf16, stride 136 (16B-aligned rows)
    const int tid = threadIdx.x;
    const int r  = tid >> 4;
    const int c8 = (tid & 15) * 8;
    const int rowbase = blockIdx.x * 16;      // grid = NV/16 exact
    float4 p0 = *((const float4*)(x + (size_t)(rowbase + r) * NF + c8));
    float4 p1 = *((const float4*)(x + (size_t)(rowbase + r) * NF + c8 + 4));
    *((ushort4*)&xs[r][c8])     = pack4(p0.x, p0.y, p0.z, p0.w);
    *((ushort4*)&xs[r][c8 + 4]) = pack4(p1.x, p1.y, p1.z, p1.w);
    __syncthreads();
    const int lane = tid & 63;
    const int wv   = tid >> 6;
    const int quad = lane >> 4;
    const int cl   = lane & 15;
    f32x4 acc = {0.f, 0.f, 0.f, 0.f};
#pragma unroll
    for (int kb = 0; kb < 4; ++kb) {
        bf16x8 a = *((const bf16x8*)&xs[cl][kb * 32 + quad * 8]);
        bf16x8 b = *((const bf16x8*)(W0frag + ((size_t)(wv * 4 + kb) * 64 + lane) * 8));
        acc = __builtin_amdgcn_mfma_f32_16x16x32_bf16(a, b, acc, 0, 0, 0);
    }
    const int col = wv * 16 + cl;
    const float bo = b0[col];
#pragma unroll
    for (int p = 0; p < 4; ++p) {
        const int orow = quad * 4 + p;
        float o = acc[p] + bo;
        o = o > 0.f ? o : 0.f;
        unsigned short ob = f2bf(o);
        const size_t idx = (size_t)(rowbase + orow) * NH + col;
        Xbf[idx]  = ob;
        X0bf[idx] = ob;
    }
}

// ---------------- v->e gather: 2x 8-lane subgroups, stream-4, packed accum ----
__global__ __launch_bounds__(256) void gather_ve(const int* __restrict__ rs_e,
                                                 const int* __restrict__ vid_sorted,
                                                 const unsigned short* __restrict__ Xbf,
                                                 const float* __restrict__ scaleE,
                                                 unsigned short* __restrict__ Xebf) {
    const int tid = threadIdx.x;
    const int l8  = tid & 7;
    const int e = blockIdx.x * 16 + (tid >> 4);   // grid = NE/16 exact
    const int sb = rs_e[e];
    const int se = rs_e[e + 1];
    const int h  = (se - sb + 1) >> 1;
    int m        = sb + ((tid & 8) ? h : 0);
    const int en = (tid & 8) ? se : (sb + h);
    f32x2 a[4] = {{0.f, 0.f}, {0.f, 0.f}, {0.f, 0.f}, {0.f, 0.f}};
    if (m + 4 <= en) {
        int i0 = vid_sorted[m], i1 = vid_sorted[m + 1];
        int i2 = vid_sorted[m + 2], i3 = vid_sorted[m + 3];
        m += 4;
        while (m + 4 <= en) {
            int j0 = vid_sorted[m], j1 = vid_sorted[m + 1];
            int j2 = vid_sorted[m + 2], j3 = vid_sorted[m + 3];
            m += 4;
            uint4 p = *((const uint4*)(Xbf + i0) + l8);
            uint4 q = *((const uint4*)(Xbf + i1) + l8);
            uint4 u = *((const uint4*)(Xbf + i2) + l8);
            uint4 t = *((const uint4*)(Xbf + i3) + l8);
            accp(a, p); accp(a, q); accp(a, u); accp(a, t);
            i0 = j0; i1 = j1; i2 = j2; i3 = j3;
        }
        uint4 p = *((const uint4*)(Xbf + i0) + l8);
        uint4 q = *((const uint4*)(Xbf + i1) + l8);
        uint4 u = *((const uint4*)(Xbf + i2) + l8);
        uint4 t = *((const uint4*)(Xbf + i3) + l8);
        accp(a, p); accp(a, q); accp(a, u); accp(a, t);
    }
    for (; m < en; ++m) {
        uint4 p = *((const uint4*)(Xbf + vid_sorted[m]) + l8);
        accp(a, p);
    }
#pragma unroll
    for (int j = 0; j < 4; ++j) {            // combine halves
        a[j].x += __shfl_xor(a[j].x, 8);
        a[j].y += __shfl_xor(a[j].y, 8);
    }
    if (!(tid & 8)) {
        const float s = scaleE[e];
        u16x8 o;
#pragma unroll
        for (int j = 0; j < 4; ++j) {
            o[2 * j]     = f2bf(a[j].x * s);
            o[2 * j + 1] = f2bf(a[j].y * s);
        }
        *((u16x8*)(Xebf + (size_t)e * NH) + l8) = o;
    }
}

// ---------------- e->v gather + normalize/residual + MFMA MLP (+head) ----------
template <bool LAST>
__global__ __launch_bounds__(256) void gather_ev_update(const int* __restrict__ rs_v,
                                                        const int* __restrict__ eid_sorted,
                                                        const unsigned short* __restrict__ Xebf,
                                                        const float* __restrict__ degV,
                                                        const unsigned short* __restrict__ X0bf,
                                                        const unsigned short* __restrict__ WfragL,
                                                        unsigned short* __restrict__ Xbf,
                                                        float beta,
                                                        const unsigned short* __restrict__ WfragH,
                                                        const float* __restrict__ bout,
                                                        float* __restrict__ outp) {
    __shared__ unsigned short xis_bf[16][72];              // bf16, stride 72 (2-way only)
    __shared__ unsigned short xo_bf[LAST ? 16 * 72 : 1];   // final X (LAST only)
    __shared__ float lg[LAST ? 16 * 48 : 1];               // logits (LAST only)
    const int tid = threadIdx.x;
    const int l8  = tid & 7;
    const int r   = tid >> 4;
    const int v = blockIdx.x * 16 + r;        // grid = NV/16 exact
    const int sb  = rs_v[v];
    const int sen = rs_v[v + 1];
    const float dv = degV[v];
    const int h  = (sen - sb + 1) >> 1;
    int m        = sb + ((tid & 8) ? h : 0);
    const int en = (tid & 8) ? sen : (sb + h);
    f32x2 a[4] = {{0.f, 0.f}, {0.f, 0.f}, {0.f, 0.f}, {0.f, 0.f}};
    if (m + 4 <= en) {
        int i0 = eid_sorted[m], i1 = eid_sorted[m + 1];
        int i2 = eid_sorted[m + 2], i3 = eid_sorted[m + 3];
        m += 4;
        while (m + 4 <= en) {
            int j0 = eid_sorted[m], j1 = eid_sorted[m + 1];
            int j2 = eid_sorted[m + 2], j3 = eid_sorted[m + 3];
            m += 4;
            uint4 p = *((const uint4*)(Xebf + i0) + l8);
            uint4 q = *((const uint4*)(Xebf + i1) + l8);
            uint4 u = *((const uint4*)(Xebf + i2) + l8);
            uint4 t = *((const uint4*)(Xebf + i3) + l8);
            accp(a, p); accp(a, q); accp(a, u); accp(a, t);
            i0 = j0; i1 = j1; i2 = j2; i3 = j3;
        }
        uint4 p = *((const uint4*)(Xebf + i0) + l8);
        uint4 q = *((const uint4*)(Xebf + i1) + l8);
        uint4 u = *((const uint4*)(Xebf + i2) + l8);
        uint4 t = *((const uint4*)(Xebf + i3) + l8);
        accp(a, p); accp(a, q); accp(a, u); accp(a, t);
    }
    for (; m < en; ++m) {
        uint4 p = *((const uint4*)(Xebf + eid_sorted[m]) + l8);
        accp(a, p);
    }
#pragma unroll
    for (int j = 0; j < 4; ++j) {            // combine halves, scale by degV
        a[j].x += __shfl_xor(a[j].x, 8);
        a[j].y += __shfl_xor(a[j].y, 8);
        a[j].x *= dv;
        a[j].y *= dv;
    }
    float sq = 0.f;
#pragma unroll
    for (int j = 0; j < 4; ++j) sq += a[j].x * a[j].x + a[j].y * a[j].y;
    sq += __shfl_xor(sq, 1);                  // only 1/2/4: halves are duplicates
    sq += __shfl_xor(sq, 2);
    sq += __shfl_xor(sq, 4);
    float norm = sqrtf(sq);
    float inv = norm > 0.f ? 1.f / norm : 0.f;
    u16x8 x0 = *((const u16x8*)(X0bf + (size_t)v * NH) + l8);
    if (!(tid & 8)) {
        u16x8 o;
#pragma unroll
        for (int j = 0; j < 4; ++j) {
            o[2 * j]     = f2bf(0.9f * a[j].x * inv + 0.1f * bf2f(x0[2 * j]));
            o[2 * j + 1] = f2bf(0.9f * a[j].y * inv + 0.1f * bf2f(x0[2 * j + 1]));
        }
        *((u16x8*)&xis_bf[r][l8 * 8]) = o;
    }
    __syncthreads();

    // ---- MFMA MLP: g = xi @ Wl  (M=16, N=64, K=64) ----
    const int lane = tid & 63;
    const int wv   = tid >> 6;
    const int quad = lane >> 4;
    const int cl   = lane & 15;
    bf16x8 bw0 = *((const bf16x8*)(WfragL + ((size_t)(wv * 2 + 0) * 64 + lane) * 8));
    bf16x8 bw1 = *((const bf16x8*)(WfragL + ((size_t)(wv * 2 + 1) * 64 + lane) * 8));
    bf16x8 a0 = *((const bf16x8*)&xis_bf[cl][quad * 8]);
    bf16x8 a1 = *((const bf16x8*)&xis_bf[cl][32 + quad * 8]);
    f32x4 acc = {0.f, 0.f, 0.f, 0.f};
    acc = __builtin_amdgcn_mfma_f32_16x16x32_bf16(a0, bw0, acc, 0, 0, 0);
    acc = __builtin_amdgcn_mfma_f32_16x16x32_bf16(a1, bw1, acc, 0, 0, 0);

    const float ob = 1.f - beta;
    const int col = wv * 16 + cl;
#pragma unroll
    for (int p = 0; p < 4; ++p) {
        const int row = quad * 4 + p;
        float xiv = bf2f(xis_bf[row][col]);
        float o = ob * xiv + beta * acc[p];
        o = o > 0.f ? o : 0.f;
        if (!LAST) {
            Xbf[(size_t)(blockIdx.x * 16 + row) * NH + col] = f2bf(o);
        } else {
            xo_bf[row * 72 + col] = f2bf(o);
        }
    }
    if (LAST) {
        __syncthreads();
        // ---- MFMA output head: logits = Xfinal @ Wout (N padded to 64) ----
        bf16x8 bh0 = *((const bf16x8*)(WfragH + ((size_t)(wv * 2 + 0) * 64 + lane) * 8));
        bf16x8 bh1 = *((const bf16x8*)(WfragH + ((size_t)(wv * 2 + 1) * 64 + lane) * 8));
        bf16x8 ah0 = *((const bf16x8*)&xo_bf[cl * 72 + quad * 8]);
        bf16x8 ah1 = *((const bf16x8*)&xo_bf[cl * 72 + 32 + quad * 8]);
        f32x4 acch = {0.f, 0.f, 0.f, 0.f};
        acch = __builtin_amdgcn_mfma_f32_16x16x32_bf16(ah0, bh0, acch, 0, 0, 0);
        acch = __builtin_amdgcn_mfma_f32_16x16x32_bf16(ah1, bh1, acch, 0, 0, 0);
        if (col < NC) {
            float bo = bout[col];
#pragma unroll
            for (int p = 0; p < 4; ++p) lg[(quad * 4 + p) * 48 + col] = acch[p] + bo;
        }
        __syncthreads();
        // ---- log_softmax: each wave handles 4 rows ----
        const int r0 = wv * 4;
        const bool act = lane < NC;
        float a0s = act ? lg[(r0 + 0) * 48 + lane] : -INFINITY;
        float a1s = act ? lg[(r0 + 1) * 48 + lane] : -INFINITY;
        float a2s = act ? lg[(r0 + 2) * 48 + lane] : -INFINITY;
        float a3s = act ? lg[(r0 + 3) * 48 + lane] : -INFINITY;
        float m0 = a0s, m1 = a1s, m2 = a2s, m3 = a3s;
#pragma unroll
        for (int o = 32; o; o >>= 1) {
            m0 = fmaxf(m0, __shfl_xor(m0, o));
            m1 = fmaxf(m1, __shfl_xor(m1, o));
            m2 = fmaxf(m2, __shfl_xor(m2, o));
            m3 = fmaxf(m3, __shfl_xor(m3, o));
        }
        float e0 = act ? expf(a0s - m0) : 0.f;
        float e1 = act ? expf(a1s - m1) : 0.f;
        float e2 = act ? expf(a2s - m2) : 0.f;
        float e3 = act ? expf(a3s - m3) : 0.f;
#pragma unroll
        for (int o = 32; o; o >>= 1) {
            e0 += __shfl_xor(e0, o);
            e1 += __shfl_xor(e1, o);
            e2 += __shfl_xor(e2, o);
            e3 += __shfl_xor(e3, o);
        }
        if (act) {
            const size_t vb = (size_t)(blockIdx.x * 16 + r0) * NC + lane;
            outp[vb + 0 * NC] = a0s - m0 - logf(e0);
            outp[vb + 1 * NC] = a1s - m1 - logf(e1);
            outp[vb + 2 * NC] = a2s - m2 - logf(e2);
            outp[vb + 3 * NC] = a3s - m3 - logf(e3);
        }
    }
}

extern "C" void kernel_launch(void* const* d_in, const int* in_sizes, int n_in,
                              void* d_out, int out_size, void* d_ws, size_t ws_size,
                              hipStream_t stream) {
    const float* x    = (const float*)d_in[0];
    const float* degE = (const float*)d_in[1];
    const float* degV = (const float*)d_in[2];
    const float* W0   = (const float*)d_in[3];
    const float* b0   = (const float*)d_in[4];
    const float* Ws   = (const float*)d_in[5];
    const float* Wout = (const float*)d_in[6];
    const float* bout = (const float*)d_in[7];
    const int* vertex = (const int*)d_in[8];
    const int* edges  = (const int*)d_in[9];
    float* out = (float*)d_out;

    // workspace layout
    float* scaleE = (float*)d_ws;                              // NEg
    unsigned short* Xbf  = (unsigned short*)(scaleE + NEg);    // NV*NH bf16
    unsigned short* X0bf = Xbf + (size_t)NV * NH;
    unsigned short* Xebf = X0bf + (size_t)NV * NH;             // NE*NH bf16
    int* cnt_be = (int*)(Xebf + (size_t)NEg * NH);
    int* cnt_bv = cnt_be + NBE;
    int* rsb_e  = cnt_bv + NBV;
    int* rsb_v  = rsb_e + (NBE + 1);
    int* rs_e   = rsb_v + (NBV + 1);
    int* rs_v   = rs_e + (NEg + 1);
    int* vid_sorted = rs_v + (NV + 1);                         // NNZ
    int* eid_sorted = vid_sorted + NNZp;                       // NNZ
    unsigned short* Wfrag = (unsigned short*)(eid_sorted + NNZp);  // 56 groups * 512
    int* bhist = (int*)(Wfrag + 56 * 512);                     // PBLK*SB
    int* abase = bhist + (size_t)PBLK * SB;                    // PBLK*SB

    // ---- CSR build + weight fragments ----
    hipMemsetAsync(cnt_be, 0, (size_t)(NBE + NBV) * sizeof(int), stream);
    make_wfrag<<<14, 256, 0, stream>>>(Ws, Wout, W0, Wfrag);
    coarse_hist<<<PBLK, 256, 0, stream>>>(vertex, edges, cnt_be, cnt_bv, bhist);
    scan_buckets<<<2, 512, 0, stream>>>(cnt_be, cnt_bv, rsb_e, rsb_v, rs_e, rs_v);
    colscan<<<SB, 512, 0, stream>>>(bhist, rsb_e, rsb_v, abase);
    partition_both<<<PBLK, 512, 0, stream>>>(vertex, edges, bhist, abase,
                                             vid_sorted, eid_sorted);
    local_sort_both<<<NBE + NBV, 512, 0, stream>>>(rsb_e, rsb_v, vid_sorted, eid_sorted,
                                                   rs_e, rs_v, degE, scaleE);

    // ---- X = relu(x @ W0 + b0) via MFMA ----
    gemm0_kernel<<<NV / 16, 256, 0, stream>>>(x, Wfrag + 40 * 512, b0, Xbf, X0bf);

    const float betas[4] = {logf(0.5f / 1.f + 1.f), logf(0.5f / 2.f + 1.f),
                            logf(0.5f / 3.f + 1.f), logf(0.5f / 4.f + 1.f)};

    for (int i = 0; i < 3; ++i) {
        gather_ve<<<NEg / 16, 256, 0, stream>>>(rs_e, vid_sorted, Xbf, scaleE, Xebf);
        gather_ev_update<false><<<NV / 16, 256, 0, stream>>>(rs_v, eid_sorted, Xebf, degV,
                                                             X0bf, Wfrag + (size_t)i * 4096,
                                                             Xbf, betas[i],
                                                             nullptr, nullptr, nullptr);
    }
    gather_ve<<<NEg / 16, 256, 0, stream>>>(rs_e, vid_sorted, Xbf, scaleE, Xebf);
    gather_ev_update<true><<<NV / 16, 256, 0, stream>>>(rs_v, eid_sorted, Xebf, degV,
                                                        X0bf, Wfrag + (size_t)3 * 4096,
                                                        Xbf, betas[3],
                                                        Wfrag + 16384, bout, out);
}